// Round 14
// baseline (962.137 us; speedup 1.0000x reference)
//
#include <hip/hip_runtime.h>
#include <math.h>

static inline int cdiv(int a, int b) { return (a + b - 1) / b; }

typedef __attribute__((ext_vector_type(8))) short short8;
typedef __attribute__((ext_vector_type(4))) float floatx4;
typedef unsigned short ushort4e __attribute__((ext_vector_type(4)));

#define HMAXN 30720   // static LDS table capacity (N=30000 fits; 122880 B < 160 KiB)
#define HB 128        // histogram / scatter blocks (identical edge slicing)

__device__ inline unsigned short f2bf(float f) {
    unsigned int u = __float_as_uint(f);
    unsigned int r = (u + 0x7fffu + ((u >> 16) & 1u)) >> 16;
    return (unsigned short)r;
}
__device__ inline float bf2f(unsigned short u) {
    return __uint_as_float(((unsigned int)u) << 16);
}

// ---------------- CSR build (atomic-free scatter via per-block LDS offset tables) ----------------

__global__ __launch_bounds__(256) void k_hist(const int* __restrict__ ei, int E, int N,
                                              int* __restrict__ partial) {
    __shared__ int h[HMAXN];
    for (int i = threadIdx.x; i < N; i += 256) h[i] = 0;
    __syncthreads();
    int per = (E + gridDim.x - 1) / gridDim.x;
    int beg = blockIdx.x * per;
    int end = beg + per; if (end > E) end = E;
    for (int e = beg + threadIdx.x; e < end; e += 256) {
        int s = ei[e], d = ei[E + e];
        atomicAdd(&h[d], 1);                       // in-degree (cnt)
        if (s != d) atomicAdd(&h[s], 0x10000);     // out-degree excluding self (deg)
    }
    __syncthreads();
    int* outp = partial + (size_t)blockIdx.x * N;
    for (int i = threadIdx.x; i < N; i += 256) outp[i] = h[i];
}

__global__ __launch_bounds__(256) void k_hist_glob(const int* __restrict__ ei, int E,
                                                   int* __restrict__ hist) {
    int e = blockIdx.x * 256 + threadIdx.x;
    if (e >= E) return;
    int s = ei[e], d = ei[E + e];
    atomicAdd(&hist[d], 1);
    if (s != d) atomicAdd(&hist[s], 0x10000);
}

__global__ __launch_bounds__(256) void k_hist_reduce(const int* __restrict__ partial,
                                                     int* __restrict__ hist, int N, int B) {
    int i = blockIdx.x * 256 + threadIdx.x;
    if (i >= N) return;
    int s = 0;
    for (int b = 0; b < B; b++) s += partial[(size_t)b * N + i];
    hist[i] = s;
}

// padded scan: segments rounded to x8 (dummy edges = zero records -> contribute +0.0)
__global__ __launch_bounds__(1024) void k_scan(const int* __restrict__ hist, int* __restrict__ row_ptr,
                                               int N) {
    __shared__ int part[1024];
    int t = threadIdx.x;
    int chunk = (N + 1023) / 1024;
    int beg = t * chunk;
    int end = beg + chunk; if (end > N) end = N;
    int s = 0;
    for (int i = beg; i < end; i++) s += ((hist[i] & 0xffff) + 7) & ~7;
    part[t] = s;
    __syncthreads();
    for (int off = 1; off < 1024; off <<= 1) {
        int v = (t >= off) ? part[t - off] : 0;
        __syncthreads();
        part[t] += v;
        __syncthreads();
    }
    int base = (t > 0) ? part[t - 1] : 0;
    for (int i = beg; i < end; i++) { row_ptr[i] = base; base += ((hist[i] & 0xffff) + 7) & ~7; }
    if (t == 1023) row_ptr[N] = part[1023];
}

__global__ __launch_bounds__(256) void k_off(const int* __restrict__ partial,
                                             const int* __restrict__ row_ptr,
                                             int* __restrict__ off, int N, int B) {
    int i = blockIdx.x * 256 + threadIdx.x;
    if (i >= N) return;
    int run = row_ptr[i];
    for (int b = 0; b < B; b++) {
        off[(size_t)b * N + i] = run;
        run += partial[(size_t)b * N + i] & 0xffff;
    }
}

__global__ __launch_bounds__(256) void k_scatter2(const int* __restrict__ ei, int E, int N,
                                                  const int* __restrict__ hist,
                                                  const int* __restrict__ off,
                                                  int2* __restrict__ erec, int Epad) {
    __shared__ int h[HMAXN];
    const int* offb = off + (size_t)blockIdx.x * N;
    for (int i = threadIdx.x; i < N; i += 256) h[i] = offb[i];
    __syncthreads();
    int per = (E + gridDim.x - 1) / gridDim.x;
    int beg = blockIdx.x * per;
    int end = beg + per; if (end > E) end = E;
    for (int e = beg + threadIdx.x; e < end; e += 256) {
        int s = ei[e], d = ei[E + e];
        float v = 0.f;
        if (s != d) {
            int a = hist[s] >> 16, b = hist[d] >> 16;
            float fa = (a > 0) ? 1.f / sqrtf((float)a) : 0.f;
            float fb = (b > 0) ? 1.f / sqrtf((float)b) : 0.f;
            v = -fa * fb;
        }
        int pos = atomicAdd(&h[d], 1);   // LDS atomic
        if (pos < Epad) erec[pos] = make_int2(s, __float_as_int(v));
    }
}

__global__ __launch_bounds__(256) void k_scatter_glob(const int* __restrict__ ei, int E,
                                                      const int* __restrict__ hist,
                                                      const int* __restrict__ row_ptr,
                                                      int* __restrict__ fill,
                                                      int2* __restrict__ erec, int Epad) {
    int e = blockIdx.x * 256 + threadIdx.x;
    if (e >= E) return;
    int s = ei[e], d = ei[E + e];
    float v = 0.f;
    if (s != d) {
        int a = hist[s] >> 16, b = hist[d] >> 16;
        float fa = (a > 0) ? 1.f / sqrtf((float)a) : 0.f;
        float fb = (b > 0) ? 1.f / sqrtf((float)b) : 0.f;
        v = -fa * fb;
    }
    int pos = row_ptr[d] + atomicAdd(&fill[d], 1);
    if (pos < Epad) erec[pos] = make_int2(s, __float_as_int(v));
}

// -------- weight convert, all 6 layers in one dispatch --------
// W[K][Cin][Cout] fp32 -> WT[Cout][K*slot] bf16, slot = ceil(Cin/32)*32 (k zero-padded to slot)

__global__ __launch_bounds__(256) void k_wconv6(const float* __restrict__ W0, const float* __restrict__ W1,
                                                const float* __restrict__ W2, const float* __restrict__ W3,
                                                const float* __restrict__ W4, const float* __restrict__ W5,
                                                unsigned short* __restrict__ T0, unsigned short* __restrict__ T1,
                                                unsigned short* __restrict__ T2, unsigned short* __restrict__ T3,
                                                unsigned short* __restrict__ T4, unsigned short* __restrict__ T5) {
    const int Cin[6]  = {128, 190, 256, 169, 190, 256};
    const int Cout[6] = {190, 256, 169, 190, 256, 128};
    const int Kt[6]   = {2, 2, 2, 5, 1, 3};
    const int Slot[6] = {128, 192, 256, 192, 192, 256};
    const float* Ws[6] = {W0, W1, W2, W3, W4, W5};
    unsigned short* Ts[6] = {T0, T1, T2, T3, T4, T5};
    int li = blockIdx.y;
    int sl = Slot[li];
    int ldk = Kt[li] * sl;
    int total = Cout[li] * ldk;
    int idx = blockIdx.x * 256 + threadIdx.x;
    if (idx >= total) return;
    int n = idx / ldk;
    int rem = idx - n * ldk;
    int term = rem / sl;
    int k = rem - term * sl;
    float v = (k < Cin[li]) ? Ws[li][(size_t)term * Cin[li] * Cout[li] + (size_t)k * Cout[li] + n] : 0.f;
    Ts[li][idx] = f2bf(v);
}

// ---------------- x (fp32, ld 128) -> wide bf16, stride 256, cols 0..127 ----------------

__global__ __launch_bounds__(128) void k_x0(const float* __restrict__ x, unsigned short* __restrict__ xb, int N) {
    int n = blockIdx.x;
    int c = threadIdx.x;
    xb[(size_t)n * 256 + c] = f2bf(x[(size_t)n * 128 + c]);
}

// ---------------- wave-per-node propagation (bf16 gather, fp32 accumulate) ----------------
// C4 = slot/4 so slot pads (zeros in the source) propagate as exact zeros.
// Measured: bandwidth-proportional at ~3.4-3.8 TB/s random-gather ceiling (fp32 round 3 vs
// bf16 round 13) -> at its floor for this precision/layout.

__global__ __launch_bounds__(256) void k_prop_w(const unsigned short* __restrict__ in,
                                                unsigned short* __restrict__ outb,
                                                float* __restrict__ outf,
                                                const unsigned short* __restrict__ tm2b,
                                                const float* __restrict__ tm2f,
                                                const int* __restrict__ row_ptr,
                                                const int2* __restrict__ erec,
                                                int C4, int Nn, int ld4, int gslog) {
    const int node = blockIdx.x * (256 >> gslog) + (threadIdx.x >> gslog);
    if (node >= Nn) return;
    const int lane4 = threadIdx.x & ((1 << gslog) - 1);
    if (lane4 >= C4) return;

    int beg = row_ptr[node], end = row_ptr[node + 1];
    const ushort4e* h4 = (const ushort4e*)in;
    float a0 = 0.f, a1 = 0.f, a2 = 0.f, a3 = 0.f;
    for (int j = beg; j < end; j += 8) {
        int4 r0 = *(const int4*)&erec[j];
        int4 r1 = *(const int4*)&erec[j + 2];
        int4 r2 = *(const int4*)&erec[j + 4];
        int4 r3 = *(const int4*)&erec[j + 6];
        ushort4e v0 = h4[(size_t)r0.x * ld4 + lane4];
        ushort4e v1 = h4[(size_t)r0.z * ld4 + lane4];
        ushort4e v2 = h4[(size_t)r1.x * ld4 + lane4];
        ushort4e v3 = h4[(size_t)r1.z * ld4 + lane4];
        ushort4e v4 = h4[(size_t)r2.x * ld4 + lane4];
        ushort4e v5 = h4[(size_t)r2.z * ld4 + lane4];
        ushort4e v6 = h4[(size_t)r3.x * ld4 + lane4];
        ushort4e v7 = h4[(size_t)r3.z * ld4 + lane4];
        float n0 = __int_as_float(r0.y), n1 = __int_as_float(r0.w);
        float n2 = __int_as_float(r1.y), n3 = __int_as_float(r1.w);
        float n4 = __int_as_float(r2.y), n5 = __int_as_float(r2.w);
        float n6 = __int_as_float(r3.y), n7 = __int_as_float(r3.w);
        a0 += n0 * bf2f(v0.x) + n1 * bf2f(v1.x) + n2 * bf2f(v2.x) + n3 * bf2f(v3.x)
            + n4 * bf2f(v4.x) + n5 * bf2f(v5.x) + n6 * bf2f(v6.x) + n7 * bf2f(v7.x);
        a1 += n0 * bf2f(v0.y) + n1 * bf2f(v1.y) + n2 * bf2f(v2.y) + n3 * bf2f(v3.y)
            + n4 * bf2f(v4.y) + n5 * bf2f(v5.y) + n6 * bf2f(v6.y) + n7 * bf2f(v7.y);
        a2 += n0 * bf2f(v0.z) + n1 * bf2f(v1.z) + n2 * bf2f(v2.z) + n3 * bf2f(v3.z)
            + n4 * bf2f(v4.z) + n5 * bf2f(v5.z) + n6 * bf2f(v6.z) + n7 * bf2f(v7.z);
        a3 += n0 * bf2f(v0.w) + n1 * bf2f(v1.w) + n2 * bf2f(v2.w) + n3 * bf2f(v3.w)
            + n4 * bf2f(v4.w) + n5 * bf2f(v5.w) + n6 * bf2f(v6.w) + n7 * bf2f(v7.w);
    }
    if (tm2b) {
        ushort4e t = ((const ushort4e*)tm2b)[(size_t)node * ld4 + lane4];
        a0 = 2.f * a0 - bf2f(t.x); a1 = 2.f * a1 - bf2f(t.y);
        a2 = 2.f * a2 - bf2f(t.z); a3 = 2.f * a3 - bf2f(t.w);
    } else if (tm2f) {
        float4 t = ((const float4*)tm2f)[(size_t)node * 48 + lane4];
        a0 = 2.f * a0 - t.x; a1 = 2.f * a1 - t.y; a2 = 2.f * a2 - t.z; a3 = 2.f * a3 - t.w;
    }
    ushort4e r;
    r.x = f2bf(a0); r.y = f2bf(a1); r.z = f2bf(a2); r.w = f2bf(a3);
    ((ushort4e*)outb)[(size_t)node * ld4 + lane4] = r;
    if (outf) ((float4*)outf)[(size_t)node * 48 + lane4] = make_float4(a0, a1, a2, a3);
}

// ------- wide bf16 MFMA GEMM, BM=128 x BN=64 tile -------
// BN=64 (was 128): grid 2x -> fixes 17% occupancy (grid-limited), and for Cout=190/169 the
// column cover is 192 not 256 (-25% wasted MFMA). 4 waves, each 32 rows x 64 cols (acc[2][4]).
// stats path: Y fp32 (stride 256) + fused column sum/sumsq.
// fused-ReLU path: bf16 to hb at stride ldo; cols [Cout, cpad) written as EXACT ZEROS.

__global__ __launch_bounds__(256, 2) void k_gemm_w(const unsigned short* __restrict__ A, int lda,
                                                   const unsigned short* __restrict__ WT,
                                                   const float* __restrict__ bias,
                                                   float* __restrict__ Y,
                                                   float* __restrict__ stats,
                                                   unsigned short* __restrict__ hb, int ldo, int cpad,
                                                   int M, int Kp, int Cout) {
    __shared__ unsigned short As[128][40];
    __shared__ unsigned short Bs[64][40];
    const int t = threadIdx.x;
    const int bm = blockIdx.y * 128, bn = blockIdx.x * 64;
    const int w = t >> 6, lane = t & 63;
    const int fr = lane & 15, fg = lane >> 4;
    const int srow = t >> 2;        // 0..63
    const int skq = (t & 3) * 8;    // 0,8,16,24

    floatx4 acc[2][4];
#pragma unroll
    for (int i = 0; i < 2; i++)
#pragma unroll
        for (int j = 0; j < 4; j++) acc[i][j] = (floatx4){0.f, 0.f, 0.f, 0.f};

    for (int k0 = 0; k0 < Kp; k0 += 32) {
#pragma unroll
        for (int p = 0; p < 2; p++) {
            int r = p * 64 + srow;
            int grow = bm + r;
            uint4 av = make_uint4(0u, 0u, 0u, 0u);
            if (grow < M) av = *(const uint4*)&A[(size_t)grow * lda + k0 + skq];
            *(uint4*)&As[r][skq] = av;
        }
        {
            int gn = bn + srow;
            uint4 bv = make_uint4(0u, 0u, 0u, 0u);
            if (gn < Cout) bv = *(const uint4*)&WT[(size_t)gn * lda + k0 + skq];
            *(uint4*)&Bs[srow][skq] = bv;
        }
        __syncthreads();

        short8 a[2], b[4];
#pragma unroll
        for (int i = 0; i < 2; i++) a[i] = *(const short8*)&As[32 * w + 16 * i + fr][fg * 8];
#pragma unroll
        for (int j = 0; j < 4; j++) b[j] = *(const short8*)&Bs[16 * j + fr][fg * 8];
#pragma unroll
        for (int i = 0; i < 2; i++)
#pragma unroll
            for (int j = 0; j < 4; j++)
                acc[i][j] = __builtin_amdgcn_mfma_f32_16x16x32_bf16(a[i], b[j], acc[i][j], 0, 0, 0);
        __syncthreads();
    }

    // epilogue: C/D layout col=lane&15, row=(lane>>4)*4+q; wave rows = bm+32w..+32
    if (stats) {
        float s1[4] = {0.f, 0.f, 0.f, 0.f};
        float s2[4] = {0.f, 0.f, 0.f, 0.f};
#pragma unroll
        for (int j = 0; j < 4; j++) {
            int c = bn + 16 * j + fr;
#pragma unroll
            for (int i = 0; i < 2; i++) {
#pragma unroll
                for (int q = 0; q < 4; q++) {
                    int r = bm + 32 * w + 16 * i + fg * 4 + q;
                    float v = 0.f;
                    if (r < M && c < Cout) {
                        v = acc[i][j][q] + bias[c];
                        Y[(size_t)r * 256 + c] = v;
                    }
                    s1[j] += v;
                    s2[j] += v * v;
                }
            }
        }
#pragma unroll
        for (int j = 0; j < 4; j++) {
            s1[j] += __shfl_xor(s1[j], 16, 64);
            s1[j] += __shfl_xor(s1[j], 32, 64);
            s2[j] += __shfl_xor(s2[j], 16, 64);
            s2[j] += __shfl_xor(s2[j], 32, 64);
            if (fg == 0) {
                int c = bn + 16 * j + fr;
                if (c < Cout) {
                    atomicAdd(&stats[c], s1[j]);
                    atomicAdd(&stats[256 + c], s2[j]);
                }
            }
        }
    } else {
        // fused ReLU -> bf16; zero-fill cols [Cout, cpad); never write c >= cpad
#pragma unroll
        for (int j = 0; j < 4; j++) {
            int c = bn + 16 * j + fr;
            if (c >= cpad) continue;
            float bc = (c < Cout) ? bias[c] : 0.f;
#pragma unroll
            for (int i = 0; i < 2; i++) {
#pragma unroll
                for (int q = 0; q < 4; q++) {
                    int r = bm + 32 * w + 16 * i + fg * 4 + q;
                    if (r < M) {
                        float v = (c < Cout) ? fmaxf(acc[i][j][q] + bc, 0.f) : 0.f;
                        hb[(size_t)r * ldo + c] = f2bf(v);
                    }
                }
            }
        }
    }
}

// ---- GraphNorm affine + leaky(0.2), coeffs computed inline from stats (k_coeffs folded in) ----
// reads Yb (fp32, stride 256), writes bf16 at stride ldo, zero-filling slot pad cols [C, Cpad)

__global__ __launch_bounds__(256) void k_act(const float* __restrict__ Y, unsigned short* __restrict__ hb,
                                             int ldo, const float* __restrict__ stats,
                                             const float* __restrict__ w, const float* __restrict__ b,
                                             const float* __restrict__ ms,
                                             int N, int C, int Cpad) {
    int n = blockIdx.x;
    int c = threadIdx.x;
    if (c >= Cpad) return;
    float v = 0.f;
    if (c < C) {
        float m = stats[c] / (float)N;
        float q = stats[256 + c] / (float)N;
        float msv = ms[c];
        float var = q - m * m * msv * (2.f - msv);
        float sc = w[c] / sqrtf(var + 1e-5f);
        float off = b[c] - sc * m * msv;
        v = Y[(size_t)n * 256 + c] * sc + off;
        v = (v > 0.f) ? v : 0.2f * v;
    }
    hb[(size_t)n * ldo + c] = f2bf(v);
}

// ---------------- pooling (sorted batch -> segmented run reduction, stride 128) + head --------

__global__ __launch_bounds__(128) void k_pool3(const unsigned short* __restrict__ hb, const int* __restrict__ batch,
                                               float* __restrict__ pooled, float* __restrict__ cntg, int N) {
    int t = threadIdx.x;
    int beg = blockIdx.x * 32;
    int end = beg + 32; if (end > N) end = N;
    if (beg >= N) return;
    int cur = batch[beg];
    float acc = 0.f;
    int runlen = 0;
    for (int n = beg; n < end; n++) {
        int b = batch[n];
        if (b != cur) {
            atomicAdd(&pooled[cur * 128 + t], acc);
            if (t == 0) atomicAdd(&cntg[cur], (float)runlen);
            acc = 0.f; runlen = 0; cur = b;
        }
        acc += bf2f(hb[(size_t)n * 128 + t]);
        runlen++;
    }
    atomicAdd(&pooled[cur * 128 + t], acc);
    if (t == 0) atomicAdd(&cntg[cur], (float)runlen);
}

__global__ __launch_bounds__(128) void k_head(const float* __restrict__ pooled, const float* __restrict__ cntg,
                                              const float* __restrict__ W1, const float* __restrict__ b1,
                                              const float* __restrict__ W2, const float* __restrict__ b2,
                                              float* __restrict__ out) {
    __shared__ float p[128];
    __shared__ float h1[64];
    int g = blockIdx.x;
    int t = threadIdx.x;
    float c = cntg[g];
    if (c < 1.f) c = 1.f;
    p[t] = pooled[g * 128 + t] / c;
    __syncthreads();
    if (t < 64) {
        float s = b1[t];
        for (int i = 0; i < 128; i++) s += p[i] * W1[i * 64 + t];
        h1[t] = tanhf(s);
    }
    __syncthreads();
    if (t < 10) {
        float s = b2[t];
        for (int i = 0; i < 64; i++) s += h1[i] * W2[i * 10 + t];
        out[g * 10 + t] = s;
    }
}

// ---------------- orchestration ----------------

extern "C" void kernel_launch(void* const* d_in, const int* in_sizes, int n_in,
                              void* d_out, int out_size, void* d_ws, size_t ws_size,
                              hipStream_t stream) {
    const float* x = (const float*)d_in[0];
    const int* ei = (const int*)d_in[1];
    const int* batch = (const int*)d_in[2];
    const float* convW[6]; const float* convB[6];
    for (int i = 0; i < 6; i++) { convW[i] = (const float*)d_in[3 + 2 * i]; convB[i] = (const float*)d_in[4 + 2 * i]; }
    const float* bnW[4]; const float* bnB[4]; const float* bnMS[4];
    for (int i = 0; i < 4; i++) { bnW[i] = (const float*)d_in[15 + 3 * i]; bnB[i] = (const float*)d_in[16 + 3 * i]; bnMS[i] = (const float*)d_in[17 + 3 * i]; }
    const float* lin1w = (const float*)d_in[27]; const float* lin1b = (const float*)d_in[28];
    const float* lin2w = (const float*)d_in[29]; const float* lin2b = (const float*)d_in[30];
    float* out = (float*)d_out;

    const int N = in_sizes[0] / 128;
    const int E = in_sizes[1] / 2;
    const int G = out_size / 10;
    const int Epad = E + 8 * N;

    struct LayerDef { int K, Cin, Cout, bn; };
    const LayerDef L[6] = {
        {2, 128, 190, 0},
        {2, 190, 256, 1},
        {2, 256, 169, 2},
        {5, 169, 190, -1},
        {1, 190, 256, -1},
        {3, 256, 128, 3},
    };
    const int slot[6]   = {128, 192, 256, 192, 192, 256};   // ceil(Cin/32)*32
    const int stride[6] = {256, 384, 512, 960, 192, 768};   // K * slot

    char* p = (char*)d_ws;
    auto alloc = [&](size_t bytes) -> void* { void* r = (void*)p; p += (bytes + 255) & ~(size_t)255; return r; };
    unsigned short* wide = (unsigned short*)alloc((size_t)N * 960 * 2);   // all Chebyshev terms, bf16
    float* Yb  = (float*)alloc((size_t)N * 256 * 4);                      // GN-layer GEMM out; doubles as L4->L5 bf16 buf
    float* B1f = (float*)alloc((size_t)N * 192 * 4);                      // fp32 tm2 copies (layer 4)
    float* B2f = (float*)alloc((size_t)N * 192 * 4);
    // ---- contiguous zero-region (single memset at launch start) ----
    char* zbeg = p;
    int* fill = (int*)alloc((size_t)N * 4);                // used only by fallback path
    int2* erec = (int2*)alloc((size_t)Epad * 8);           // interleaved (src, norm) records
    float* stats4 = (float*)alloc(4 * 512 * 4);            // per-GN-layer stats slices
    float* pooled = (float*)alloc((size_t)G * 129 * 4);
    float* cntg = pooled + (size_t)G * 128;
    int* hist = (int*)alloc((size_t)N * 4);
    size_t zlen = (size_t)(p - zbeg);
    // ---- end zero-region ----
    int* row_ptr = (int*)alloc((size_t)(N + 1) * 4);
    int* partial = (int*)alloc((size_t)HB * N * 4);
    int* offt = (int*)alloc((size_t)HB * N * 4);
    unsigned short* WT[6];
    for (int i = 0; i < 6; i++) WT[i] = (unsigned short*)alloc((size_t)L[i].Cout * stride[i] * 2);

    hipMemsetAsync(zbeg, 0, zlen, stream);   // fill, erec, stats4, pooled, cntg, hist
    if (N <= HMAXN) {
        k_hist<<<HB, 256, 0, stream>>>(ei, E, N, partial);
        k_hist_reduce<<<cdiv(N, 256), 256, 0, stream>>>(partial, hist, N, HB);
        k_scan<<<1, 1024, 0, stream>>>(hist, row_ptr, N);
        k_off<<<cdiv(N, 256), 256, 0, stream>>>(partial, row_ptr, offt, N, HB);
        k_scatter2<<<HB, 256, 0, stream>>>(ei, E, N, hist, offt, erec, Epad);
    } else {
        k_hist_glob<<<cdiv(E, 256), 256, 0, stream>>>(ei, E, hist);
        k_scan<<<1, 1024, 0, stream>>>(hist, row_ptr, N);
        k_scatter_glob<<<cdiv(E, 256), 256, 0, stream>>>(ei, E, hist, row_ptr, fill, erec, Epad);
    }
    {
        dim3 wg(713, 6);  // 713 = cdiv(max layer total = 190*960, 256)
        k_wconv6<<<wg, 256, 0, stream>>>(convW[0], convW[1], convW[2], convW[3], convW[4], convW[5],
                                         WT[0], WT[1], WT[2], WT[3], WT[4], WT[5]);
    }
    k_x0<<<N, 128, 0, stream>>>(x, wide, N);

    auto prop = [&](const unsigned short* in, unsigned short* outb, float* outf,
                    const unsigned short* tm2b, const float* tm2f, int C4, int ld4) {
        int gslog = (C4 <= 32) ? 5 : 6;
        int npb = 256 >> gslog;
        k_prop_w<<<cdiv(N, npb), 256, 0, stream>>>(in, outb, outf, tm2b, tm2f, row_ptr,
                                                   erec, C4, N, ld4, gslog);
    };

    for (int li = 0; li < 6; li++) {
        const int K = L[li].K, Cout = L[li].Cout;
        const int st = stride[li], ld4 = st / 4;
        const int sl = slot[li], C4 = sl / 4;
        const unsigned short* src = (li == 4) ? (const unsigned short*)Yb : wide;  // L5 reads Yb-as-bf16

        if (K >= 2)  // T1 = prop(T0)
            prop(src, wide + sl, (li == 3) ? B1f : nullptr, nullptr, nullptr, C4, ld4);
        if (K >= 3)  // T2 = 2*prop(T1) - T0
            prop(wide + sl, wide + 2 * sl, (li == 3) ? B2f : nullptr, wide, nullptr, C4, ld4);
        if (li == 3) {
            // T3 = 2*prop(T2) - T1 (fp32 tm2 = B1f; overwrite B1f with T3 fp32)
            prop(wide + 2 * sl, wide + 3 * sl, B1f, nullptr, B1f, C4, ld4);
            // T4 = 2*prop(T3) - T2 (fp32 tm2 = B2f)
            prop(wide + 3 * sl, wide + 4 * sl, nullptr, nullptr, B2f, C4, ld4);
        }

        const int bnidx = L[li].bn;
        dim3 gg(cdiv(Cout, 64), cdiv(N, 128));
        if (bnidx >= 0) {
            float* stats = stats4 + bnidx * 512;   // pre-zeroed by the launch-wide memset
            k_gemm_w<<<gg, 256, 0, stream>>>(src, st, WT[li], convB[li], Yb, stats,
                                             nullptr, 0, 0, N, st, Cout);
            // act computes coeffs inline and writes NEXT layer's T0 slot (zero-filling slot pad)
            const int nxt_ld = (li < 5) ? stride[li + 1] : 128;
            const int nxt_cp = (li < 5) ? slot[li + 1] : 128;
            k_act<<<N, 256, 0, stream>>>(Yb, wide, nxt_ld, stats,
                                         bnW[bnidx], bnB[bnidx], bnMS[bnidx], N, Cout, nxt_cp);
        } else if (li == 3) {
            // fused ReLU -> Yb-as-bf16 at L5's stride 192; cols 190..191 zero-filled
            k_gemm_w<<<gg, 256, 0, stream>>>(wide, st, WT[li], convB[li], nullptr, nullptr,
                                             (unsigned short*)Yb, stride[4], slot[4], N, st, Cout);
        } else {
            // li==4: fused ReLU -> wide stride 768 = L6's T0 (slot 256, Cout 256: no pad)
            k_gemm_w<<<gg, 256, 0, stream>>>((const unsigned short*)Yb, st, WT[li], convB[li],
                                             nullptr, nullptr, wide, stride[5], slot[5], N, st, Cout);
        }
    }

    k_pool3<<<cdiv(N, 32), 128, 0, stream>>>(wide, batch, pooled, cntg, N);
    k_head<<<G, 128, 0, stream>>>(pooled, cntg, lin1w, lin1b, lin2w, lin2b, out);
}

// Round 15
// 934.931 us; speedup vs baseline: 1.0291x; 1.0291x over previous
//
#include <hip/hip_runtime.h>
#include <math.h>

static inline int cdiv(int a, int b) { return (a + b - 1) / b; }

typedef __attribute__((ext_vector_type(8))) short short8;
typedef __attribute__((ext_vector_type(4))) float floatx4;
typedef unsigned short ushort4e __attribute__((ext_vector_type(4)));

#define HMAXN 30720   // static LDS table capacity (N=30000 fits; 122880 B < 160 KiB)
#define HB 128        // histogram / scatter blocks (identical edge slicing)

__device__ inline unsigned short f2bf(float f) {
    unsigned int u = __float_as_uint(f);
    unsigned int r = (u + 0x7fffu + ((u >> 16) & 1u)) >> 16;
    return (unsigned short)r;
}
__device__ inline float bf2f(unsigned short u) {
    return __uint_as_float(((unsigned int)u) << 16);
}

// ---------------- CSR build (atomic-free scatter via per-block LDS offset tables) ----------------

__global__ __launch_bounds__(256) void k_hist(const int* __restrict__ ei, int E, int N,
                                              int* __restrict__ partial) {
    __shared__ int h[HMAXN];
    for (int i = threadIdx.x; i < N; i += 256) h[i] = 0;
    __syncthreads();
    int per = (E + gridDim.x - 1) / gridDim.x;
    int beg = blockIdx.x * per;
    int end = beg + per; if (end > E) end = E;
    for (int e = beg + threadIdx.x; e < end; e += 256) {
        int s = ei[e], d = ei[E + e];
        atomicAdd(&h[d], 1);                       // in-degree (cnt)
        if (s != d) atomicAdd(&h[s], 0x10000);     // out-degree excluding self (deg)
    }
    __syncthreads();
    int* outp = partial + (size_t)blockIdx.x * N;
    for (int i = threadIdx.x; i < N; i += 256) outp[i] = h[i];
}

__global__ __launch_bounds__(256) void k_hist_glob(const int* __restrict__ ei, int E,
                                                   int* __restrict__ hist) {
    int e = blockIdx.x * 256 + threadIdx.x;
    if (e >= E) return;
    int s = ei[e], d = ei[E + e];
    atomicAdd(&hist[d], 1);
    if (s != d) atomicAdd(&hist[s], 0x10000);
}

__global__ __launch_bounds__(256) void k_hist_reduce(const int* __restrict__ partial,
                                                     int* __restrict__ hist, int N, int B) {
    int i = blockIdx.x * 256 + threadIdx.x;
    if (i >= N) return;
    int s = 0;
    for (int b = 0; b < B; b++) s += partial[(size_t)b * N + i];
    hist[i] = s;
}

// padded scan: segments rounded to x8 (dummy edges = zero records -> contribute +0.0)
__global__ __launch_bounds__(1024) void k_scan(const int* __restrict__ hist, int* __restrict__ row_ptr,
                                               int N) {
    __shared__ int part[1024];
    int t = threadIdx.x;
    int chunk = (N + 1023) / 1024;
    int beg = t * chunk;
    int end = beg + chunk; if (end > N) end = N;
    int s = 0;
    for (int i = beg; i < end; i++) s += ((hist[i] & 0xffff) + 7) & ~7;
    part[t] = s;
    __syncthreads();
    for (int off = 1; off < 1024; off <<= 1) {
        int v = (t >= off) ? part[t - off] : 0;
        __syncthreads();
        part[t] += v;
        __syncthreads();
    }
    int base = (t > 0) ? part[t - 1] : 0;
    for (int i = beg; i < end; i++) { row_ptr[i] = base; base += ((hist[i] & 0xffff) + 7) & ~7; }
    if (t == 1023) row_ptr[N] = part[1023];
}

__global__ __launch_bounds__(256) void k_off(const int* __restrict__ partial,
                                             const int* __restrict__ row_ptr,
                                             int* __restrict__ off, int N, int B) {
    int i = blockIdx.x * 256 + threadIdx.x;
    if (i >= N) return;
    int run = row_ptr[i];
    for (int b = 0; b < B; b++) {
        off[(size_t)b * N + i] = run;
        run += partial[(size_t)b * N + i] & 0xffff;
    }
}

__global__ __launch_bounds__(256) void k_scatter2(const int* __restrict__ ei, int E, int N,
                                                  const int* __restrict__ hist,
                                                  const int* __restrict__ off,
                                                  int2* __restrict__ erec, int Epad) {
    __shared__ int h[HMAXN];
    const int* offb = off + (size_t)blockIdx.x * N;
    for (int i = threadIdx.x; i < N; i += 256) h[i] = offb[i];
    __syncthreads();
    int per = (E + gridDim.x - 1) / gridDim.x;
    int beg = blockIdx.x * per;
    int end = beg + per; if (end > E) end = E;
    for (int e = beg + threadIdx.x; e < end; e += 256) {
        int s = ei[e], d = ei[E + e];
        float v = 0.f;
        if (s != d) {
            int a = hist[s] >> 16, b = hist[d] >> 16;
            float fa = (a > 0) ? 1.f / sqrtf((float)a) : 0.f;
            float fb = (b > 0) ? 1.f / sqrtf((float)b) : 0.f;
            v = -fa * fb;
        }
        int pos = atomicAdd(&h[d], 1);   // LDS atomic
        if (pos < Epad) erec[pos] = make_int2(s, __float_as_int(v));
    }
}

__global__ __launch_bounds__(256) void k_scatter_glob(const int* __restrict__ ei, int E,
                                                      const int* __restrict__ hist,
                                                      const int* __restrict__ row_ptr,
                                                      int* __restrict__ fill,
                                                      int2* __restrict__ erec, int Epad) {
    int e = blockIdx.x * 256 + threadIdx.x;
    if (e >= E) return;
    int s = ei[e], d = ei[E + e];
    float v = 0.f;
    if (s != d) {
        int a = hist[s] >> 16, b = hist[d] >> 16;
        float fa = (a > 0) ? 1.f / sqrtf((float)a) : 0.f;
        float fb = (b > 0) ? 1.f / sqrtf((float)b) : 0.f;
        v = -fa * fb;
    }
    int pos = row_ptr[d] + atomicAdd(&fill[d], 1);
    if (pos < Epad) erec[pos] = make_int2(s, __float_as_int(v));
}

// -------- weight convert, all 6 layers in one dispatch --------
// W[K][Cin][Cout] fp32 -> WT[Cout][K*slot] bf16, slot = ceil(Cin/32)*32 (k zero-padded to slot)

__global__ __launch_bounds__(256) void k_wconv6(const float* __restrict__ W0, const float* __restrict__ W1,
                                                const float* __restrict__ W2, const float* __restrict__ W3,
                                                const float* __restrict__ W4, const float* __restrict__ W5,
                                                unsigned short* __restrict__ T0, unsigned short* __restrict__ T1,
                                                unsigned short* __restrict__ T2, unsigned short* __restrict__ T3,
                                                unsigned short* __restrict__ T4, unsigned short* __restrict__ T5) {
    const int Cin[6]  = {128, 190, 256, 169, 190, 256};
    const int Cout[6] = {190, 256, 169, 190, 256, 128};
    const int Kt[6]   = {2, 2, 2, 5, 1, 3};
    const int Slot[6] = {128, 192, 256, 192, 192, 256};
    const float* Ws[6] = {W0, W1, W2, W3, W4, W5};
    unsigned short* Ts[6] = {T0, T1, T2, T3, T4, T5};
    int li = blockIdx.y;
    int sl = Slot[li];
    int ldk = Kt[li] * sl;
    int total = Cout[li] * ldk;
    int idx = blockIdx.x * 256 + threadIdx.x;
    if (idx >= total) return;
    int n = idx / ldk;
    int rem = idx - n * ldk;
    int term = rem / sl;
    int k = rem - term * sl;
    float v = (k < Cin[li]) ? Ws[li][(size_t)term * Cin[li] * Cout[li] + (size_t)k * Cout[li] + n] : 0.f;
    Ts[li][idx] = f2bf(v);
}

// ---------------- x (fp32, ld 128) -> wide bf16, stride 256, cols 0..127 ----------------

__global__ __launch_bounds__(128) void k_x0(const float* __restrict__ x, unsigned short* __restrict__ xb, int N) {
    int n = blockIdx.x;
    int c = threadIdx.x;
    xb[(size_t)n * 256 + c] = f2bf(x[(size_t)n * 128 + c]);
}

// ---------------- wave-per-node propagation (bf16 gather, fp32 accumulate) ----------------
// Measured bandwidth-proportional at the ~3.4-3.8 TB/s random-gather fabric ceiling.

__global__ __launch_bounds__(256) void k_prop_w(const unsigned short* __restrict__ in,
                                                unsigned short* __restrict__ outb,
                                                float* __restrict__ outf,
                                                const unsigned short* __restrict__ tm2b,
                                                const float* __restrict__ tm2f,
                                                const int* __restrict__ row_ptr,
                                                const int2* __restrict__ erec,
                                                int C4, int Nn, int ld4, int gslog) {
    const int node = blockIdx.x * (256 >> gslog) + (threadIdx.x >> gslog);
    if (node >= Nn) return;
    const int lane4 = threadIdx.x & ((1 << gslog) - 1);
    if (lane4 >= C4) return;

    int beg = row_ptr[node], end = row_ptr[node + 1];
    const ushort4e* h4 = (const ushort4e*)in;
    float a0 = 0.f, a1 = 0.f, a2 = 0.f, a3 = 0.f;
    for (int j = beg; j < end; j += 8) {
        int4 r0 = *(const int4*)&erec[j];
        int4 r1 = *(const int4*)&erec[j + 2];
        int4 r2 = *(const int4*)&erec[j + 4];
        int4 r3 = *(const int4*)&erec[j + 6];
        ushort4e v0 = h4[(size_t)r0.x * ld4 + lane4];
        ushort4e v1 = h4[(size_t)r0.z * ld4 + lane4];
        ushort4e v2 = h4[(size_t)r1.x * ld4 + lane4];
        ushort4e v3 = h4[(size_t)r1.z * ld4 + lane4];
        ushort4e v4 = h4[(size_t)r2.x * ld4 + lane4];
        ushort4e v5 = h4[(size_t)r2.z * ld4 + lane4];
        ushort4e v6 = h4[(size_t)r3.x * ld4 + lane4];
        ushort4e v7 = h4[(size_t)r3.z * ld4 + lane4];
        float n0 = __int_as_float(r0.y), n1 = __int_as_float(r0.w);
        float n2 = __int_as_float(r1.y), n3 = __int_as_float(r1.w);
        float n4 = __int_as_float(r2.y), n5 = __int_as_float(r2.w);
        float n6 = __int_as_float(r3.y), n7 = __int_as_float(r3.w);
        a0 += n0 * bf2f(v0.x) + n1 * bf2f(v1.x) + n2 * bf2f(v2.x) + n3 * bf2f(v3.x)
            + n4 * bf2f(v4.x) + n5 * bf2f(v5.x) + n6 * bf2f(v6.x) + n7 * bf2f(v7.x);
        a1 += n0 * bf2f(v0.y) + n1 * bf2f(v1.y) + n2 * bf2f(v2.y) + n3 * bf2f(v3.y)
            + n4 * bf2f(v4.y) + n5 * bf2f(v5.y) + n6 * bf2f(v6.y) + n7 * bf2f(v7.y);
        a2 += n0 * bf2f(v0.z) + n1 * bf2f(v1.z) + n2 * bf2f(v2.z) + n3 * bf2f(v3.z)
            + n4 * bf2f(v4.z) + n5 * bf2f(v5.z) + n6 * bf2f(v6.z) + n7 * bf2f(v7.z);
        a3 += n0 * bf2f(v0.w) + n1 * bf2f(v1.w) + n2 * bf2f(v2.w) + n3 * bf2f(v3.w)
            + n4 * bf2f(v4.w) + n5 * bf2f(v5.w) + n6 * bf2f(v6.w) + n7 * bf2f(v7.w);
    }
    if (tm2b) {
        ushort4e t = ((const ushort4e*)tm2b)[(size_t)node * ld4 + lane4];
        a0 = 2.f * a0 - bf2f(t.x); a1 = 2.f * a1 - bf2f(t.y);
        a2 = 2.f * a2 - bf2f(t.z); a3 = 2.f * a3 - bf2f(t.w);
    } else if (tm2f) {
        float4 t = ((const float4*)tm2f)[(size_t)node * 48 + lane4];
        a0 = 2.f * a0 - t.x; a1 = 2.f * a1 - t.y; a2 = 2.f * a2 - t.z; a3 = 2.f * a3 - t.w;
    }
    ushort4e r;
    r.x = f2bf(a0); r.y = f2bf(a1); r.z = f2bf(a2); r.w = f2bf(a3);
    ((ushort4e*)outb)[(size_t)node * ld4 + lane4] = r;
    if (outf) ((float4*)outf)[(size_t)node * 48 + lane4] = make_float4(a0, a1, a2, a3);
}

// ------- bf16 MFMA GEMM, BM=128 x BN (templated 64/128) -------
// BN picked per layer: 64 where it trims wasted cols (Cout 190/169 -> cover 192), 128 where
// it minimizes A re-fetch (Cout 256/128). Output always bf16 (stride ldo):
//   stats != null: y + fused column sum/sumsq (stats from fp32, y rounded to bf16)
//   stats == null: fused ReLU; cols [Cout, cpad) written as EXACT ZEROS (NaN discipline).

template <int BN>
__global__ __launch_bounds__(256, 2) void k_gemm_t(const unsigned short* __restrict__ A, int lda,
                                                   const unsigned short* __restrict__ WT,
                                                   const float* __restrict__ bias,
                                                   float* __restrict__ stats,
                                                   unsigned short* __restrict__ outw, int ldo, int cpad,
                                                   int M, int Kp, int Cout) {
    constexpr int WC = BN / 64;     // waves along cols: 2 (BN128) / 1 (BN64)
    constexpr int WR = 4 / WC;      // waves along rows: 2 / 4
    constexpr int RW = 128 / WR;    // rows per wave: 64 / 32
    constexpr int MI = RW / 16;     // row frags per wave: 4 / 2
    __shared__ unsigned short As[128][40];
    __shared__ unsigned short Bs[BN][40];
    const int t = threadIdx.x;
    const int bm = blockIdx.y * 128, bn = blockIdx.x * BN;
    const int w = t >> 6, lane = t & 63;
    const int wr = w / WC, wc = w % WC;
    const int fr = lane & 15, fg = lane >> 4;
    const int srow = t >> 2;        // 0..63
    const int skq = (t & 3) * 8;    // 0,8,16,24

    floatx4 acc[MI][4];
#pragma unroll
    for (int i = 0; i < MI; i++)
#pragma unroll
        for (int j = 0; j < 4; j++) acc[i][j] = (floatx4){0.f, 0.f, 0.f, 0.f};

    for (int k0 = 0; k0 < Kp; k0 += 32) {
#pragma unroll
        for (int p = 0; p < 2; p++) {
            int r = p * 64 + srow;
            int grow = bm + r;
            uint4 av = make_uint4(0u, 0u, 0u, 0u);
            if (grow < M) av = *(const uint4*)&A[(size_t)grow * lda + k0 + skq];
            *(uint4*)&As[r][skq] = av;
        }
#pragma unroll
        for (int p = 0; p < BN / 64; p++) {
            int r = p * 64 + srow;
            int gn = bn + r;
            uint4 bv = make_uint4(0u, 0u, 0u, 0u);
            if (gn < Cout) bv = *(const uint4*)&WT[(size_t)gn * lda + k0 + skq];
            *(uint4*)&Bs[r][skq] = bv;
        }
        __syncthreads();

        short8 a[MI], b[4];
#pragma unroll
        for (int i = 0; i < MI; i++) a[i] = *(const short8*)&As[RW * wr + 16 * i + fr][fg * 8];
#pragma unroll
        for (int j = 0; j < 4; j++) b[j] = *(const short8*)&Bs[64 * wc + 16 * j + fr][fg * 8];
#pragma unroll
        for (int i = 0; i < MI; i++)
#pragma unroll
            for (int j = 0; j < 4; j++)
                acc[i][j] = __builtin_amdgcn_mfma_f32_16x16x32_bf16(a[i], b[j], acc[i][j], 0, 0, 0);
        __syncthreads();
    }

    // epilogue: C/D layout col=lane&15, row=(lane>>4)*4+q
    float s1[4] = {0.f, 0.f, 0.f, 0.f};
    float s2[4] = {0.f, 0.f, 0.f, 0.f};
#pragma unroll
    for (int j = 0; j < 4; j++) {
        int c = bn + 64 * wc + 16 * j + fr;
        float bc = (c < Cout) ? bias[c] : 0.f;
#pragma unroll
        for (int i = 0; i < MI; i++) {
#pragma unroll
            for (int q = 0; q < 4; q++) {
                int r = bm + RW * wr + 16 * i + fg * 4 + q;
                float v = 0.f;
                if (r < M && c < Cout) v = acc[i][j][q] + bc;
                if (stats) { s1[j] += v; s2[j] += v * v; }
                else v = fmaxf(v, 0.f);
                if (r < M && c < cpad) outw[(size_t)r * ldo + c] = f2bf(v);
            }
        }
    }
    if (stats) {
#pragma unroll
        for (int j = 0; j < 4; j++) {
            s1[j] += __shfl_xor(s1[j], 16, 64);
            s1[j] += __shfl_xor(s1[j], 32, 64);
            s2[j] += __shfl_xor(s2[j], 16, 64);
            s2[j] += __shfl_xor(s2[j], 32, 64);
            if (fg == 0) {
                int c = bn + 64 * wc + 16 * j + fr;
                if (c < Cout) {
                    atomicAdd(&stats[c], s1[j]);
                    atomicAdd(&stats[256 + c], s2[j]);
                }
            }
        }
    }
}

// ---- GraphNorm affine + leaky(0.2), coeffs computed inline from stats ----
// reads Y16 (bf16, stride 256), writes bf16 at stride ldo, zero-filling slot pad cols [C, Cpad)

__global__ __launch_bounds__(256) void k_act(const unsigned short* __restrict__ Y16,
                                             unsigned short* __restrict__ hb,
                                             int ldo, const float* __restrict__ stats,
                                             const float* __restrict__ w, const float* __restrict__ b,
                                             const float* __restrict__ ms,
                                             int N, int C, int Cpad) {
    int n = blockIdx.x;
    int c = threadIdx.x;
    if (c >= Cpad) return;
    float v = 0.f;
    if (c < C) {
        float m = stats[c] / (float)N;
        float q = stats[256 + c] / (float)N;
        float msv = ms[c];
        float var = q - m * m * msv * (2.f - msv);
        float sc = w[c] / sqrtf(var + 1e-5f);
        float off = b[c] - sc * m * msv;
        v = bf2f(Y16[(size_t)n * 256 + c]) * sc + off;
        v = (v > 0.f) ? v : 0.2f * v;
    }
    hb[(size_t)n * ldo + c] = f2bf(v);
}

// ---------------- pooling (sorted batch -> segmented run reduction, stride 128) + head --------

__global__ __launch_bounds__(128) void k_pool3(const unsigned short* __restrict__ hb, const int* __restrict__ batch,
                                               float* __restrict__ pooled, float* __restrict__ cntg, int N) {
    int t = threadIdx.x;
    int beg = blockIdx.x * 32;
    int end = beg + 32; if (end > N) end = N;
    if (beg >= N) return;
    int cur = batch[beg];
    float acc = 0.f;
    int runlen = 0;
    for (int n = beg; n < end; n++) {
        int b = batch[n];
        if (b != cur) {
            atomicAdd(&pooled[cur * 128 + t], acc);
            if (t == 0) atomicAdd(&cntg[cur], (float)runlen);
            acc = 0.f; runlen = 0; cur = b;
        }
        acc += bf2f(hb[(size_t)n * 128 + t]);
        runlen++;
    }
    atomicAdd(&pooled[cur * 128 + t], acc);
    if (t == 0) atomicAdd(&cntg[cur], (float)runlen);
}

__global__ __launch_bounds__(128) void k_head(const float* __restrict__ pooled, const float* __restrict__ cntg,
                                              const float* __restrict__ W1, const float* __restrict__ b1,
                                              const float* __restrict__ W2, const float* __restrict__ b2,
                                              float* __restrict__ out) {
    __shared__ float p[128];
    __shared__ float h1[64];
    int g = blockIdx.x;
    int t = threadIdx.x;
    float c = cntg[g];
    if (c < 1.f) c = 1.f;
    p[t] = pooled[g * 128 + t] / c;
    __syncthreads();
    if (t < 64) {
        float s = b1[t];
        for (int i = 0; i < 128; i++) s += p[i] * W1[i * 64 + t];
        h1[t] = tanhf(s);
    }
    __syncthreads();
    if (t < 10) {
        float s = b2[t];
        for (int i = 0; i < 64; i++) s += h1[i] * W2[i * 10 + t];
        out[g * 10 + t] = s;
    }
}

// ---------------- orchestration ----------------

extern "C" void kernel_launch(void* const* d_in, const int* in_sizes, int n_in,
                              void* d_out, int out_size, void* d_ws, size_t ws_size,
                              hipStream_t stream) {
    const float* x = (const float*)d_in[0];
    const int* ei = (const int*)d_in[1];
    const int* batch = (const int*)d_in[2];
    const float* convW[6]; const float* convB[6];
    for (int i = 0; i < 6; i++) { convW[i] = (const float*)d_in[3 + 2 * i]; convB[i] = (const float*)d_in[4 + 2 * i]; }
    const float* bnW[4]; const float* bnB[4]; const float* bnMS[4];
    for (int i = 0; i < 4; i++) { bnW[i] = (const float*)d_in[15 + 3 * i]; bnB[i] = (const float*)d_in[16 + 3 * i]; bnMS[i] = (const float*)d_in[17 + 3 * i]; }
    const float* lin1w = (const float*)d_in[27]; const float* lin1b = (const float*)d_in[28];
    const float* lin2w = (const float*)d_in[29]; const float* lin2b = (const float*)d_in[30];
    float* out = (float*)d_out;

    const int N = in_sizes[0] / 128;
    const int E = in_sizes[1] / 2;
    const int G = out_size / 10;
    const int Epad = E + 8 * N;

    struct LayerDef { int K, Cin, Cout, bn; };
    const LayerDef L[6] = {
        {2, 128, 190, 0},
        {2, 190, 256, 1},
        {2, 256, 169, 2},
        {5, 169, 190, -1},
        {1, 190, 256, -1},
        {3, 256, 128, 3},
    };
    const int slot[6]   = {128, 192, 256, 192, 192, 256};   // ceil(Cin/32)*32
    const int stride[6] = {256, 384, 512, 960, 192, 768};   // K * slot

    char* p = (char*)d_ws;
    auto alloc = [&](size_t bytes) -> void* { void* r = (void*)p; p += (bytes + 255) & ~(size_t)255; return r; };
    unsigned short* wide = (unsigned short*)alloc((size_t)N * 960 * 2);   // all Chebyshev terms, bf16
    unsigned short* Y16 = (unsigned short*)alloc((size_t)N * 256 * 2);    // GEMM bf16 out (GN-y / L4->L5)
    float* B1f = (float*)alloc((size_t)N * 192 * 4);                      // fp32 tm2 copies (layer 4)
    float* B2f = (float*)alloc((size_t)N * 192 * 4);
    // ---- contiguous zero-region (single memset at launch start) ----
    char* zbeg = p;
    int* fill = (int*)alloc((size_t)N * 4);                // used only by fallback path
    int2* erec = (int2*)alloc((size_t)Epad * 8);           // interleaved (src, norm) records
    float* stats4 = (float*)alloc(4 * 512 * 4);            // per-GN-layer stats slices
    float* pooled = (float*)alloc((size_t)G * 129 * 4);
    float* cntg = pooled + (size_t)G * 128;
    int* hist = (int*)alloc((size_t)N * 4);
    size_t zlen = (size_t)(p - zbeg);
    // ---- end zero-region ----
    int* row_ptr = (int*)alloc((size_t)(N + 1) * 4);
    int* partial = (int*)alloc((size_t)HB * N * 4);
    int* offt = (int*)alloc((size_t)HB * N * 4);
    unsigned short* WT[6];
    for (int i = 0; i < 6; i++) WT[i] = (unsigned short*)alloc((size_t)L[i].Cout * stride[i] * 2);

    hipMemsetAsync(zbeg, 0, zlen, stream);   // fill, erec, stats4, pooled, cntg, hist
    if (N <= HMAXN) {
        k_hist<<<HB, 256, 0, stream>>>(ei, E, N, partial);
        k_hist_reduce<<<cdiv(N, 256), 256, 0, stream>>>(partial, hist, N, HB);
        k_scan<<<1, 1024, 0, stream>>>(hist, row_ptr, N);
        k_off<<<cdiv(N, 256), 256, 0, stream>>>(partial, row_ptr, offt, N, HB);
        k_scatter2<<<HB, 256, 0, stream>>>(ei, E, N, hist, offt, erec, Epad);
    } else {
        k_hist_glob<<<cdiv(E, 256), 256, 0, stream>>>(ei, E, hist);
        k_scan<<<1, 1024, 0, stream>>>(hist, row_ptr, N);
        k_scatter_glob<<<cdiv(E, 256), 256, 0, stream>>>(ei, E, hist, row_ptr, fill, erec, Epad);
    }
    {
        dim3 wg(713, 6);  // 713 = cdiv(max layer total = 190*960, 256)
        k_wconv6<<<wg, 256, 0, stream>>>(convW[0], convW[1], convW[2], convW[3], convW[4], convW[5],
                                         WT[0], WT[1], WT[2], WT[3], WT[4], WT[5]);
    }
    k_x0<<<N, 128, 0, stream>>>(x, wide, N);

    auto prop = [&](const unsigned short* in, unsigned short* outb, float* outf,
                    const unsigned short* tm2b, const float* tm2f, int C4, int ld4) {
        int gslog = (C4 <= 32) ? 5 : 6;
        int npb = 256 >> gslog;
        k_prop_w<<<cdiv(N, npb), 256, 0, stream>>>(in, outb, outf, tm2b, tm2f, row_ptr,
                                                   erec, C4, N, ld4, gslog);
    };
    // per-layer GEMM launcher: BN=64 for Cout 190/169 (cover 192), BN=128 for Cout 256/128
    auto gemm = [&](const unsigned short* A, int lda, const unsigned short* wt, const float* bias,
                    float* stats, unsigned short* outw, int ldo, int cpad, int Cout) {
        if (Cout == 256 || Cout == 128) {
            dim3 gg(cdiv(Cout, 128), cdiv(N, 128));
            k_gemm_t<128><<<gg, 256, 0, stream>>>(A, lda, wt, bias, stats, outw, ldo, cpad, N, lda, Cout);
        } else {
            dim3 gg(cdiv(Cout, 64), cdiv(N, 128));
            k_gemm_t<64><<<gg, 256, 0, stream>>>(A, lda, wt, bias, stats, outw, ldo, cpad, N, lda, Cout);
        }
    };

    for (int li = 0; li < 6; li++) {
        const int K = L[li].K, Cout = L[li].Cout;
        const int st = stride[li], ld4 = st / 4;
        const int sl = slot[li], C4 = sl / 4;
        const unsigned short* src = (li == 4) ? Y16 : wide;   // L5 reads Y16 (stride 192)

        if (K >= 2)  // T1 = prop(T0)
            prop(src, wide + sl, (li == 3) ? B1f : nullptr, nullptr, nullptr, C4, ld4);
        if (K >= 3)  // T2 = 2*prop(T1) - T0
            prop(wide + sl, wide + 2 * sl, (li == 3) ? B2f : nullptr, wide, nullptr, C4, ld4);
        if (li == 3) {
            // T3 = 2*prop(T2) - T1 (fp32 tm2 = B1f; overwrite B1f with T3 fp32)
            prop(wide + 2 * sl, wide + 3 * sl, B1f, nullptr, B1f, C4, ld4);
            // T4 = 2*prop(T3) - T2 (fp32 tm2 = B2f)
            prop(wide + 3 * sl, wide + 4 * sl, nullptr, nullptr, B2f, C4, ld4);
        }

        const int bnidx = L[li].bn;
        if (bnidx >= 0) {
            float* stats = stats4 + bnidx * 512;   // pre-zeroed by the launch-wide memset
            // GEMM -> bf16 y (stride 256) + fused stats
            gemm(src, st, WT[li], convB[li], stats, Y16, 256, Cout, Cout);
            // act computes coeffs inline, writes NEXT layer's T0 slot (zero-filling slot pad)
            const int nxt_ld = (li < 5) ? stride[li + 1] : 128;
            const int nxt_cp = (li < 5) ? slot[li + 1] : 128;
            k_act<<<N, 256, 0, stream>>>(Y16, wide, nxt_ld, stats,
                                         bnW[bnidx], bnB[bnidx], bnMS[bnidx], N, Cout, nxt_cp);
        } else if (li == 3) {
            // fused ReLU -> Y16 at L5's stride 192; cols 190..191 zero-filled
            gemm(wide, st, WT[li], convB[li], nullptr, Y16, stride[4], slot[4], Cout);
        } else {
            // li==4: fused ReLU -> wide stride 768 = L6's T0 (slot 256, Cout 256: no pad)
            gemm(Y16, st, WT[li], convB[li], nullptr, wide, stride[5], slot[5], Cout);
        }
    }

    k_pool3<<<cdiv(N, 32), 128, 0, stream>>>(wide, batch, pooled, cntg, N);
    k_head<<<G, 128, 0, stream>>>(pooled, cntg, lin1w, lin1b, lin2w, lin2b, out);
}